// Round 1
// baseline (316.262 us; speedup 1.0000x reference)
//
#include <hip/hip_runtime.h>
#include <hip/hip_bf16.h>

// Problem constants (from reference setup_inputs)
#define BB 2
#define LL 4096
#define DD 256
#define KK 16
#define GG 4
#define HH 8
#define DH 64
#define PE 32
#define INNER 512          // H*DH
#define CC 21              // 1 + K + G
#define MM (BB*LL)         // 8192
#define SCALE 0.125f       // 64^-0.5

// ---------------------------------------------------------------------------
// K1: QKV feature GEMM.  C[M,1536] = spatial[M,256] @ [Wq | Wk[:256] | Wv[:256]]
// Tiles: BM=64, BN=64, BK=16, 256 threads, 4x4 per thread.
// ---------------------------------------------------------------------------
__global__ __launch_bounds__(256) void gemm_qkv(
    const float* __restrict__ spatial,
    const float* __restrict__ Wq, const float* __restrict__ Wk,
    const float* __restrict__ Wv,
    float* __restrict__ Qb, float* __restrict__ Kfb, float* __restrict__ Vfb)
{
    const int bm = blockIdx.x;          // 0..127
    const int bn = blockIdx.y;          // 0..23
    const int nbase = bn * 64;          // multiple of 64; never straddles a 512 segment
    const int seg  = nbase >> 9;        // 0:Q 1:K 2:V
    const int col0 = nbase & 511;
    const float* __restrict__ W  = (seg == 0) ? Wq : (seg == 1) ? Wk : Wv;
    float* __restrict__ Out      = (seg == 0) ? Qb : (seg == 1) ? Kfb : Vfb;

    __shared__ float As[16][64 + 1];    // k-major (transposed) A tile
    __shared__ float Bs[16][64];

    const int tid = threadIdx.x;
    const int tx = tid & 15;            // output col group
    const int ty = tid >> 4;            // output row group
    const int m0 = bm * 64;

    float acc[4][4] = {};

    const int ar = tid >> 2;            // 0..63
    const int ac = (tid & 3) << 2;      // 0,4,8,12
    const int br = tid >> 4;            // 0..15
    const int bc = (tid & 15) << 2;     // 0..60

    for (int k0 = 0; k0 < DD; k0 += 16) {
        float4 av = *reinterpret_cast<const float4*>(&spatial[(m0 + ar) * DD + k0 + ac]);
        As[ac + 0][ar] = av.x; As[ac + 1][ar] = av.y;
        As[ac + 2][ar] = av.z; As[ac + 3][ar] = av.w;
        float4 bv = *reinterpret_cast<const float4*>(&W[(k0 + br) * INNER + col0 + bc]);
        *reinterpret_cast<float4*>(&Bs[br][bc]) = bv;
        __syncthreads();
        #pragma unroll
        for (int kk = 0; kk < 16; ++kk) {
            float a[4], b[4];
            #pragma unroll
            for (int i = 0; i < 4; ++i) a[i] = As[kk][ty * 4 + i];
            #pragma unroll
            for (int j = 0; j < 4; ++j) b[j] = Bs[kk][tx * 4 + j];
            #pragma unroll
            for (int i = 0; i < 4; ++i)
                #pragma unroll
                for (int j = 0; j < 4; ++j)
                    acc[i][j] += a[i] * b[j];
        }
        __syncthreads();
    }
    #pragma unroll
    for (int i = 0; i < 4; ++i) {
        const int m = m0 + ty * 4 + i;
        float4 v = { acc[i][0], acc[i][1], acc[i][2], acc[i][3] };
        *reinterpret_cast<float4*>(&Out[m * INNER + col0 + tx * 4]) = v;
    }
}

// ---------------------------------------------------------------------------
// K1b: global-latent K/V projection (8 rows only; rpe part is zero for globals)
// ---------------------------------------------------------------------------
__global__ __launch_bounds__(256) void gemm_globals(
    const float* __restrict__ gl, const float* __restrict__ Wk,
    const float* __restrict__ Wv, float* __restrict__ Kg, float* __restrict__ Vg)
{
    const int bg = blockIdx.x;          // 0..7  (b*G + g)
    const int tid = threadIdx.x;
    const float* __restrict__ x = &gl[bg * DD];
    for (int rep = 0; rep < 2; ++rep) {
        const int n = tid + rep * 256;
        float sk = 0.f, sv = 0.f;
        for (int k = 0; k < DD; ++k) {
            const float xv = x[k];
            sk += xv * Wk[k * INNER + n];
            sv += xv * Wv[k * INNER + n];
        }
        Kg[bg * INNER + n] = sk;
        Vg[bg * INNER + n] = sv;
    }
}

// ---------------------------------------------------------------------------
// K2: per-query attention. One block (256 threads) per query.
//   logit[h,c] = (Q_h . Kf_gather_h  +  rpe_c . t_h) * SCALE + bias[h,c]
//   t[h,p]     = sum_d Wk[256+p, h*64+d] * Q[h*64+d]
//   out[j]     = sum_c w[h,c] * Vf_gather[c][j]  +  sum_p rbar[h,p] * Wv[256+p, j]
//   rbar[h,p]  = sum_{c<17} w[h,c] * rpe_c[p]
// ---------------------------------------------------------------------------
__global__ __launch_bounds__(256) void attn_kernel(
    const float* __restrict__ Qb, const float* __restrict__ Kf,
    const float* __restrict__ Vf, const float* __restrict__ Kg,
    const float* __restrict__ Vg, const int* __restrict__ topk,
    const float* __restrict__ rpe, const float* __restrict__ self_rpe,
    const float* __restrict__ distances, const float* __restrict__ Wk,
    const float* __restrict__ Wv, const float* __restrict__ log_sigma,
    const float* __restrict__ global_bias, float* __restrict__ obuf)
{
    const int q = blockIdx.x;           // 0..8191 = b*L + l
    const int b = q >> 12;              // L = 4096
    const int tid = threadIdx.x;

    __shared__ float q_sh[INNER];
    __shared__ float t_sh[HH][PE];
    __shared__ float logits[HH][24];
    __shared__ float wgt[HH][24];
    __shared__ float rbar[HH][PE];
    __shared__ int   rows[CC];
    __shared__ float distsh[CC];
    __shared__ float sig2[HH];

    q_sh[tid]       = Qb[q * INNER + tid];
    q_sh[tid + 256] = Qb[q * INNER + 256 + tid];
    if (tid < CC) {
        int m; float dist;
        if (tid == 0)      { m = q; dist = 0.f; }
        else if (tid < 17) {
            const int idx = topk[q * KK + tid - 1];
            m = b * LL + idx;
            dist = distances[q * KK + tid - 1];
        } else               { m = -1; dist = 0.f; }
        rows[tid] = m; distsh[tid] = dist;
    }
    if (tid < HH) sig2[tid] = __expf(2.f * log_sigma[tid]);
    __syncthreads();

    // t[h][p]
    {
        const int h = tid >> 5, p = tid & 31;
        const float* __restrict__ wrow = &Wk[(DD + p) * INNER + h * DH];
        const float* __restrict__ qh = &q_sh[h * DH];
        float s = 0.f;
        #pragma unroll
        for (int d = 0; d < DH; ++d) s += wrow[d] * qh[d];
        t_sh[h][p] = s;
    }
    __syncthreads();

    // logits: thread = c*8 + h
    if (tid < CC * HH) {
        const int c = tid >> 3, h = tid & 7;
        const float* __restrict__ krow =
            (rows[c] >= 0) ? &Kf[(long)rows[c] * INNER] : &Kg[(b * GG + (c - 17)) * INNER];
        const float* __restrict__ qh = &q_sh[h * DH];
        float s = 0.f;
        #pragma unroll
        for (int d = 0; d < DH; ++d) s += qh[d] * krow[h * DH + d];
        float bias;
        if (c < 17) {
            const float* __restrict__ rv =
                (c == 0) ? &self_rpe[q * PE] : &rpe[((long)q * KK + c - 1) * PE];
            float sr = 0.f;
            #pragma unroll
            for (int p = 0; p < PE; ++p) sr += rv[p] * t_sh[h][p];
            s += sr;
            const float d2 = distsh[c] * distsh[c];
            bias = -d2 / (2.f * sig2[h]);
        } else {
            bias = global_bias[0];
        }
        logits[h][c] = s * SCALE + bias;
    }
    __syncthreads();

    // softmax over c, per head
    if (tid < HH) {
        float mx = -1e30f;
        for (int c = 0; c < CC; ++c) mx = fmaxf(mx, logits[tid][c]);
        float sum = 0.f;
        for (int c = 0; c < CC; ++c) {
            const float e = __expf(logits[tid][c] - mx);
            wgt[tid][c] = e; sum += e;
        }
        const float inv = 1.f / sum;
        for (int c = 0; c < CC; ++c) wgt[tid][c] *= inv;
    }
    __syncthreads();

    // rbar[h][p] = sum_{c<17} w[h][c] * rpe_c[p]
    {
        const int h = tid >> 5, p = tid & 31;
        float s = wgt[h][0] * self_rpe[q * PE + p];
        for (int c = 1; c < 17; ++c)
            s += wgt[h][c] * rpe[((long)q * KK + c - 1) * PE + p];
        rbar[h][p] = s;
    }
    __syncthreads();

    // output: o[q, j] for j = tid, tid+256
    for (int rep = 0; rep < 2; ++rep) {
        const int j = tid + rep * 256;
        const int h = j >> 6;
        float s = 0.f;
        #pragma unroll
        for (int c = 0; c < CC; ++c) {
            const float* __restrict__ vrow =
                (rows[c] >= 0) ? &Vf[(long)rows[c] * INNER] : &Vg[(b * GG + (c - 17)) * INNER];
            s += wgt[h][c] * vrow[j];
        }
        #pragma unroll
        for (int p = 0; p < PE; ++p) s += rbar[h][p] * Wv[(DD + p) * INNER + j];
        obuf[q * INNER + j] = s;
    }
}

// ---------------------------------------------------------------------------
// K3: output GEMM.  out[M,256] = o[M,512] @ Wo[512,256] + bo
// ---------------------------------------------------------------------------
__global__ __launch_bounds__(256) void gemm_out(
    const float* __restrict__ A, const float* __restrict__ Wo,
    const float* __restrict__ bo, float* __restrict__ Out)
{
    const int bm = blockIdx.x;          // 0..127
    const int bn = blockIdx.y;          // 0..3
    const int col0 = bn * 64;

    __shared__ float As[16][64 + 1];
    __shared__ float Bs[16][64];

    const int tid = threadIdx.x;
    const int tx = tid & 15;
    const int ty = tid >> 4;
    const int m0 = bm * 64;

    float acc[4][4] = {};

    const int ar = tid >> 2;
    const int ac = (tid & 3) << 2;
    const int br = tid >> 4;
    const int bc = (tid & 15) << 2;

    for (int k0 = 0; k0 < INNER; k0 += 16) {
        float4 av = *reinterpret_cast<const float4*>(&A[(m0 + ar) * INNER + k0 + ac]);
        As[ac + 0][ar] = av.x; As[ac + 1][ar] = av.y;
        As[ac + 2][ar] = av.z; As[ac + 3][ar] = av.w;
        float4 bv = *reinterpret_cast<const float4*>(&Wo[(k0 + br) * DD + col0 + bc]);
        *reinterpret_cast<float4*>(&Bs[br][bc]) = bv;
        __syncthreads();
        #pragma unroll
        for (int kk = 0; kk < 16; ++kk) {
            float a[4], b[4];
            #pragma unroll
            for (int i = 0; i < 4; ++i) a[i] = As[kk][ty * 4 + i];
            #pragma unroll
            for (int j = 0; j < 4; ++j) b[j] = Bs[kk][tx * 4 + j];
            #pragma unroll
            for (int i = 0; i < 4; ++i)
                #pragma unroll
                for (int j = 0; j < 4; ++j)
                    acc[i][j] += a[i] * b[j];
        }
        __syncthreads();
    }
    #pragma unroll
    for (int i = 0; i < 4; ++i) {
        const int m = m0 + ty * 4 + i;
        #pragma unroll
        for (int j = 0; j < 4; ++j) {
            const int n = col0 + tx * 4 + j;
            Out[m * DD + n] = acc[i][j] + bo[n];
        }
    }
}

// ---------------------------------------------------------------------------
extern "C" void kernel_launch(void* const* d_in, const int* in_sizes, int n_in,
                              void* d_out, int out_size, void* d_ws, size_t ws_size,
                              hipStream_t stream)
{
    const float* spatial     = (const float*)d_in[0];
    const int*   topk        = (const int*)  d_in[1];
    const float* rpe         = (const float*)d_in[2];
    const float* self_rpe    = (const float*)d_in[3];
    const float* distances   = (const float*)d_in[4];
    const float* gl          = (const float*)d_in[5];
    const float* Wq          = (const float*)d_in[6];
    const float* Wk          = (const float*)d_in[7];
    const float* Wv          = (const float*)d_in[8];
    const float* Wo          = (const float*)d_in[9];
    const float* bo          = (const float*)d_in[10];
    const float* log_sigma   = (const float*)d_in[11];
    const float* global_bias = (const float*)d_in[12];
    float* out = (float*)d_out;

    float* ws = (float*)d_ws;
    const size_t SEG = (size_t)MM * INNER;      // 4,194,304 floats = 16 MB
    float* Qb   = ws;
    float* Kf   = ws + SEG;
    float* Vf   = ws + 2 * SEG;
    float* obuf = ws + 3 * SEG;
    float* Kg   = ws + 4 * SEG;                 // 8*512 floats
    float* Vg   = Kg + BB * GG * INNER;

    gemm_qkv<<<dim3(MM / 64, (3 * INNER) / 64), 256, 0, stream>>>(
        spatial, Wq, Wk, Wv, Qb, Kf, Vf);
    gemm_globals<<<BB * GG, 256, 0, stream>>>(gl, Wk, Wv, Kg, Vg);
    attn_kernel<<<MM, 256, 0, stream>>>(
        Qb, Kf, Vf, Kg, Vg, topk, rpe, self_rpe, distances,
        Wk, Wv, log_sigma, global_bias, obuf);
    gemm_out<<<dim3(MM / 64, DD / 64), 256, 0, stream>>>(obuf, Wo, bo, out);
}

// Round 2
// 245.754 us; speedup vs baseline: 1.2869x; 1.2869x over previous
//
#include <hip/hip_runtime.h>
#include <hip/hip_bf16.h>

// Problem constants (from reference setup_inputs)
#define BB 2
#define LL 4096
#define DD 256
#define KK 16
#define GG 4
#define HH 8
#define DH 64
#define PE 32
#define INNER 512          // H*DH
#define CC 21              // 1 + K + G
#define MM (BB*LL)         // 8192
#define SCALE 0.125f       // 64^-0.5

// ---------------------------------------------------------------------------
// K1: QKV feature GEMM.  C[M,1536] = spatial[M,256] @ [Wq | Wk[:256] | Wv[:256]]
// ---------------------------------------------------------------------------
__global__ __launch_bounds__(256) void gemm_qkv(
    const float* __restrict__ spatial,
    const float* __restrict__ Wq, const float* __restrict__ Wk,
    const float* __restrict__ Wv,
    float* __restrict__ Qb, float* __restrict__ Kfb, float* __restrict__ Vfb)
{
    const int bm = blockIdx.x;
    const int bn = blockIdx.y;
    const int nbase = bn * 64;
    const int seg  = nbase >> 9;
    const int col0 = nbase & 511;
    const float* __restrict__ W  = (seg == 0) ? Wq : (seg == 1) ? Wk : Wv;
    float* __restrict__ Out      = (seg == 0) ? Qb : (seg == 1) ? Kfb : Vfb;

    __shared__ float As[16][64 + 1];
    __shared__ float Bs[16][64];

    const int tid = threadIdx.x;
    const int tx = tid & 15;
    const int ty = tid >> 4;
    const int m0 = bm * 64;

    float acc[4][4] = {};

    const int ar = tid >> 2;
    const int ac = (tid & 3) << 2;
    const int br = tid >> 4;
    const int bc = (tid & 15) << 2;

    for (int k0 = 0; k0 < DD; k0 += 16) {
        float4 av = *reinterpret_cast<const float4*>(&spatial[(m0 + ar) * DD + k0 + ac]);
        As[ac + 0][ar] = av.x; As[ac + 1][ar] = av.y;
        As[ac + 2][ar] = av.z; As[ac + 3][ar] = av.w;
        float4 bv = *reinterpret_cast<const float4*>(&W[(k0 + br) * INNER + col0 + bc]);
        *reinterpret_cast<float4*>(&Bs[br][bc]) = bv;
        __syncthreads();
        #pragma unroll
        for (int kk = 0; kk < 16; ++kk) {
            float a[4], b[4];
            #pragma unroll
            for (int i = 0; i < 4; ++i) a[i] = As[kk][ty * 4 + i];
            #pragma unroll
            for (int j = 0; j < 4; ++j) b[j] = Bs[kk][tx * 4 + j];
            #pragma unroll
            for (int i = 0; i < 4; ++i)
                #pragma unroll
                for (int j = 0; j < 4; ++j)
                    acc[i][j] += a[i] * b[j];
        }
        __syncthreads();
    }
    #pragma unroll
    for (int i = 0; i < 4; ++i) {
        const int m = m0 + ty * 4 + i;
        float4 v = { acc[i][0], acc[i][1], acc[i][2], acc[i][3] };
        *reinterpret_cast<float4*>(&Out[m * INNER + col0 + tx * 4]) = v;
    }
}

// ---------------------------------------------------------------------------
// K1b: global-latent K/V projection. grid (8,4); 256 thr: half K, half V.
// ---------------------------------------------------------------------------
__global__ __launch_bounds__(256) void gemm_globals(
    const float* __restrict__ gl, const float* __restrict__ Wk,
    const float* __restrict__ Wv, float* __restrict__ Kg, float* __restrict__ Vg)
{
    const int bg  = blockIdx.x;
    const int tid = threadIdx.x;
    const int col = blockIdx.y * 128 + (tid & 127);
    const bool isv = tid >= 128;
    const float* __restrict__ W = isv ? Wv : Wk;
    float* __restrict__ O       = isv ? Vg : Kg;
    const float* __restrict__ x = &gl[bg * DD];
    float s = 0.f;
    #pragma unroll 4
    for (int k = 0; k < DD; ++k) s += x[k] * W[k * INNER + col];
    O[bg * INNER + col] = s;
}

// ---------------------------------------------------------------------------
// K2: attention — ONE WAVE PER QUERY, no block barriers in the hot path.
// Lane l owns j = 8l..8l+8 of the 512-wide inner dim; head h = l>>3,
// rank r = l&7.  All gathers are wave-coalesced 2KB rows (2 dwordx4/lane).
// ---------------------------------------------------------------------------
__global__ __launch_bounds__(256) void attn_kernel(
    const float* __restrict__ Qb, const float* __restrict__ Kf,
    const float* __restrict__ Vf, const float* __restrict__ Kg,
    const float* __restrict__ Vg, const int* __restrict__ topk,
    const float* __restrict__ rpe, const float* __restrict__ self_rpe,
    const float* __restrict__ distances, const float* __restrict__ Wk,
    const float* __restrict__ Wv, const float* __restrict__ log_sigma,
    const float* __restrict__ global_bias, float* __restrict__ obuf)
{
    const int lane = threadIdx.x & 63;
    const int w    = threadIdx.x >> 6;
    const int q    = blockIdx.x * 4 + w;
    const int b    = q >> 12;                 // L = 4096
    const int h    = lane >> 3;
    const int r    = lane & 7;

    __shared__ float rbar_sh[4][HH][36];      // padded: row stride 36 -> no conflicts

    // Q slice in registers
    const float4* qp = reinterpret_cast<const float4*>(&Qb[(size_t)q * INNER + lane * 8]);
    const float4 qa = qp[0], qb4 = qp[1];

    // topk + distances staged in lanes 0..15
    int   tk = 0; float dl = 0.f;
    if (lane < KK) {
        tk = topk[q * KK + lane];
        dl = distances[q * KK + lane];
    }
    const float sig2  = __expf(2.f * log_sigma[h]);
    const float gbias = global_bias[0];

    // t4[i] = t[h][r*4+i],  t[h][p] = sum_j Wk_rpe[p][j] * Q[j] over head h's j
    float t4[4] = {0.f, 0.f, 0.f, 0.f};
    #pragma unroll
    for (int p = 0; p < PE; ++p) {
        const float4* wp = reinterpret_cast<const float4*>(
            &Wk[(size_t)(DD + p) * INNER + lane * 8]);
        const float4 wa = wp[0], wb = wp[1];
        float part = wa.x*qa.x + wa.y*qa.y + wa.z*qa.z + wa.w*qa.w
                   + wb.x*qb4.x + wb.y*qb4.y + wb.z*qb4.z + wb.w*qb4.w;
        part += __shfl_xor(part, 1);
        part += __shfl_xor(part, 2);
        part += __shfl_xor(part, 4);
        if (r == (p >> 2)) t4[p & 3] = part;
    }

    // -------- logits --------
    float lg[3] = { -1e30f, -1e30f, -1e30f };  // this lane owns c = r, r+8, r+16
    #pragma unroll
    for (int c = 0; c < CC; ++c) {
        const float* base;
        if (c == 0)       base = &Kf[(size_t)q * INNER];
        else if (c < 17)  { const int idx = __shfl(tk, c - 1);
                            base = &Kf[(size_t)(b * LL + idx) * INNER]; }
        else              base = &Kg[(size_t)(b * GG + (c - 17)) * INNER];
        const float4* kp = reinterpret_cast<const float4*>(base + lane * 8);
        const float4 ka = kp[0], kb = kp[1];
        float part = ka.x*qa.x + ka.y*qa.y + ka.z*qa.z + ka.w*qa.w
                   + kb.x*qb4.x + kb.y*qb4.y + kb.z*qb4.z + kb.w*qb4.w;
        if (c < 17) {
            const float* rp = (c == 0) ? &self_rpe[(size_t)q * PE]
                                       : &rpe[((size_t)q * KK + (c - 1)) * PE];
            const float4 r4 = *reinterpret_cast<const float4*>(rp + r * 4);
            part += r4.x*t4[0] + r4.y*t4[1] + r4.z*t4[2] + r4.w*t4[3];
        }
        part += __shfl_xor(part, 1);
        part += __shfl_xor(part, 2);
        part += __shfl_xor(part, 4);
        float bias;
        if (c == 0)      bias = 0.f;
        else if (c < 17) { const float d = __shfl(dl, c - 1);
                           bias = -(d * d) / (2.f * sig2); }
        else             bias = gbias;
        if (r == (c & 7)) lg[c >> 3] = part * SCALE + bias;
    }

    // -------- softmax over the 8-lane head group --------
    float mx = fmaxf(fmaxf(lg[0], lg[1]), lg[2]);
    mx = fmaxf(mx, __shfl_xor(mx, 1));
    mx = fmaxf(mx, __shfl_xor(mx, 2));
    mx = fmaxf(mx, __shfl_xor(mx, 4));
    const float e0 = __expf(lg[0] - mx);
    const float e1 = __expf(lg[1] - mx);
    const float e2 = __expf(lg[2] - mx);
    float s = e0 + e1 + e2;
    s += __shfl_xor(s, 1);
    s += __shfl_xor(s, 2);
    s += __shfl_xor(s, 4);
    const float inv = 1.f / s;
    float wloc[3] = { e0 * inv, e1 * inv, e2 * inv };

    // -------- weighted V + rbar accumulation --------
    float4 acc_a = {0.f,0.f,0.f,0.f}, acc_b = {0.f,0.f,0.f,0.f};
    float rb4[4] = {0.f, 0.f, 0.f, 0.f};
    #pragma unroll
    for (int c = 0; c < CC; ++c) {
        const float* base;
        if (c == 0)       base = &Vf[(size_t)q * INNER];
        else if (c < 17)  { const int idx = __shfl(tk, c - 1);
                            base = &Vf[(size_t)(b * LL + idx) * INNER]; }
        else              base = &Vg[(size_t)(b * GG + (c - 17)) * INNER];
        const float4* vp = reinterpret_cast<const float4*>(base + lane * 8);
        const float4 va = vp[0], vb = vp[1];
        const float wv = __shfl(wloc[c >> 3], (lane & 56) | (c & 7));
        acc_a.x += wv * va.x; acc_a.y += wv * va.y;
        acc_a.z += wv * va.z; acc_a.w += wv * va.w;
        acc_b.x += wv * vb.x; acc_b.y += wv * vb.y;
        acc_b.z += wv * vb.z; acc_b.w += wv * vb.w;
        if (c < 17) {
            const float* rp = (c == 0) ? &self_rpe[(size_t)q * PE]
                                       : &rpe[((size_t)q * KK + (c - 1)) * PE];
            const float4 r4 = *reinterpret_cast<const float4*>(rp + r * 4);
            rb4[0] += wv * r4.x; rb4[1] += wv * r4.y;
            rb4[2] += wv * r4.z; rb4[3] += wv * r4.w;
        }
    }

    // broadcast rbar within the head group via padded LDS
    *reinterpret_cast<float4*>(&rbar_sh[w][h][r * 4]) =
        make_float4(rb4[0], rb4[1], rb4[2], rb4[3]);
    __syncthreads();

    // out += sum_p rbar[h][p] * Wv_rpe[p][j]
    #pragma unroll 8
    for (int p = 0; p < PE; ++p) {
        const float rb = rbar_sh[w][h][p];
        const float4* wp = reinterpret_cast<const float4*>(
            &Wv[(size_t)(DD + p) * INNER + lane * 8]);
        const float4 wa = wp[0], wb = wp[1];
        acc_a.x += rb * wa.x; acc_a.y += rb * wa.y;
        acc_a.z += rb * wa.z; acc_a.w += rb * wa.w;
        acc_b.x += rb * wb.x; acc_b.y += rb * wb.y;
        acc_b.z += rb * wb.z; acc_b.w += rb * wb.w;
    }

    float4* op = reinterpret_cast<float4*>(&obuf[(size_t)q * INNER + lane * 8]);
    op[0] = acc_a; op[1] = acc_b;
}

// ---------------------------------------------------------------------------
// K3: output GEMM.  out[M,256] = o[M,512] @ Wo[512,256] + bo
// ---------------------------------------------------------------------------
__global__ __launch_bounds__(256) void gemm_out(
    const float* __restrict__ A, const float* __restrict__ Wo,
    const float* __restrict__ bo, float* __restrict__ Out)
{
    const int bm = blockIdx.x;
    const int bn = blockIdx.y;
    const int col0 = bn * 64;

    __shared__ float As[16][64 + 1];
    __shared__ float Bs[16][64];

    const int tid = threadIdx.x;
    const int tx = tid & 15;
    const int ty = tid >> 4;
    const int m0 = bm * 64;

    float acc[4][4] = {};

    const int ar = tid >> 2;
    const int ac = (tid & 3) << 2;
    const int br = tid >> 4;
    const int bc = (tid & 15) << 2;

    for (int k0 = 0; k0 < INNER; k0 += 16) {
        float4 av = *reinterpret_cast<const float4*>(&A[(m0 + ar) * INNER + k0 + ac]);
        As[ac + 0][ar] = av.x; As[ac + 1][ar] = av.y;
        As[ac + 2][ar] = av.z; As[ac + 3][ar] = av.w;
        float4 bv = *reinterpret_cast<const float4*>(&Wo[(k0 + br) * DD + col0 + bc]);
        *reinterpret_cast<float4*>(&Bs[br][bc]) = bv;
        __syncthreads();
        #pragma unroll
        for (int kk = 0; kk < 16; ++kk) {
            float a[4], b[4];
            #pragma unroll
            for (int i = 0; i < 4; ++i) a[i] = As[kk][ty * 4 + i];
            #pragma unroll
            for (int j = 0; j < 4; ++j) b[j] = Bs[kk][tx * 4 + j];
            #pragma unroll
            for (int i = 0; i < 4; ++i)
                #pragma unroll
                for (int j = 0; j < 4; ++j)
                    acc[i][j] += a[i] * b[j];
        }
        __syncthreads();
    }
    #pragma unroll
    for (int i = 0; i < 4; ++i) {
        const int m = m0 + ty * 4 + i;
        #pragma unroll
        for (int j = 0; j < 4; ++j) {
            const int n = col0 + tx * 4 + j;
            Out[m * DD + n] = acc[i][j] + bo[n];
        }
    }
}

// ---------------------------------------------------------------------------
extern "C" void kernel_launch(void* const* d_in, const int* in_sizes, int n_in,
                              void* d_out, int out_size, void* d_ws, size_t ws_size,
                              hipStream_t stream)
{
    const float* spatial     = (const float*)d_in[0];
    const int*   topk        = (const int*)  d_in[1];
    const float* rpe         = (const float*)d_in[2];
    const float* self_rpe    = (const float*)d_in[3];
    const float* distances   = (const float*)d_in[4];
    const float* gl          = (const float*)d_in[5];
    const float* Wq          = (const float*)d_in[6];
    const float* Wk          = (const float*)d_in[7];
    const float* Wv          = (const float*)d_in[8];
    const float* Wo          = (const float*)d_in[9];
    const float* bo          = (const float*)d_in[10];
    const float* log_sigma   = (const float*)d_in[11];
    const float* global_bias = (const float*)d_in[12];
    float* out = (float*)d_out;

    float* ws = (float*)d_ws;
    const size_t SEG = (size_t)MM * INNER;      // 16 MB each
    float* Qb   = ws;
    float* Kf   = ws + SEG;
    float* Vf   = ws + 2 * SEG;
    float* obuf = ws + 3 * SEG;
    float* Kg   = ws + 4 * SEG;
    float* Vg   = Kg + BB * GG * INNER;

    gemm_qkv<<<dim3(MM / 64, (3 * INNER) / 64), 256, 0, stream>>>(
        spatial, Wq, Wk, Wv, Qb, Kf, Vf);
    gemm_globals<<<dim3(BB * GG, 4), 256, 0, stream>>>(gl, Wk, Wv, Kg, Vg);
    attn_kernel<<<MM / 4, 256, 0, stream>>>(
        Qb, Kf, Vf, Kg, Vg, topk, rpe, self_rpe, distances,
        Wk, Wv, log_sigma, global_bias, obuf);
    gemm_out<<<dim3(MM / 64, DD / 64), 256, 0, stream>>>(obuf, Wo, bo, out);
}